// Round 11
// baseline (1795.581 us; speedup 1.0000x reference)
//
#include <hip/hip_runtime.h>
#include <hip/hip_bf16.h>
#include <math.h>

#define NNODES 100000
#define NEDGES 1600000
#define EN     1700000                      // edges + self loops
#define NBW    7                            // src windows (16384 nodes each)
#define WSHIFT 14
#define NB     (NNODES * NBW)               // total (dst,window) buckets = 700000
#define F_IN   256
#define F_MID  128
#define HID    128
#define NG     128
#define NOUT   64
#define SCAN_CHUNK 2048
#define NCHUNK2 ((NB + SCAN_CHUNK - 1) / SCAN_CHUNK)   // 342

typedef unsigned int  u32;
typedef unsigned short u16;

__device__ __forceinline__ float bfl(u32 u) { return __uint_as_float(u << 16); }
__device__ __forceinline__ float bfh(u32 u) { return __uint_as_float(u & 0xFFFF0000u); }
__device__ __forceinline__ u32 f2bf(float f) {           // round-to-nearest-even
    u32 x = __float_as_uint(f);
    return (x + 0x7FFFu + ((x >> 16) & 1u)) >> 16;
}

// ---------------------------------------------------------------- init
__global__ __launch_bounds__(256) void k_init(float* gs, float* pooled, float* ssum) {
    int i = blockIdx.x * 256 + threadIdx.x;
    if (i < NNODES) ssum[i] = 0.f;
    if (i < NG) gs[i] = 0.f;
    if (i < NG * HID) pooled[i] = 0.f;
}

__global__ __launch_bounds__(256) void k_zs(float* ssum) {
    int i = blockIdx.x * 256 + threadIdx.x;
    if (i < NNODES) ssum[i] = 0.f;
}

__global__ __launch_bounds__(256) void k_cnt_init(int* cnt2) {
    int i = blockIdx.x * 256 + threadIdx.x;
    if (i < NB) cnt2[i] = 0;
}

// ---------------------------------------------------------------- bucketed CSR build: key = dst*NBW + (src>>WSHIFT)
__global__ __launch_bounds__(256) void k_count2(const int* __restrict__ ei, int* cnt2) {
    int e = blockIdx.x * 256 + threadIdx.x;
    if (e >= EN) return;
    int src, dst;
    if (e < NEDGES) { src = ei[e]; dst = ei[NEDGES + e]; }
    else            { src = dst = e - NEDGES; }
    atomicAdd(&cnt2[dst * NBW + (src >> WSHIFT)], 1);
}

__global__ __launch_bounds__(256) void k_scan_chunk(const int* __restrict__ cnt2,
                                                    int* rowptr2, int* part) {
    __shared__ int sums[256];
    int c = blockIdx.x, t = threadIdx.x;
    int base = c * SCAN_CHUNK;
    int v[8]; int s = 0;
#pragma unroll
    for (int i = 0; i < 8; i++) {
        int idx = base + t * 8 + i;
        v[i] = (idx < NB) ? cnt2[idx] : 0;
        s += v[i];
    }
    sums[t] = s;
    __syncthreads();
    for (int off = 1; off < 256; off <<= 1) {
        int x = (t >= off) ? sums[t - off] : 0;
        __syncthreads();
        sums[t] += x;
        __syncthreads();
    }
    int run = (t == 0) ? 0 : sums[t - 1];
#pragma unroll
    for (int i = 0; i < 8; i++) {
        int idx = base + t * 8 + i;
        if (idx < NB) rowptr2[idx] = run;
        run += v[i];
    }
    if (t == 255) part[c] = sums[255];
}

__global__ void k_scan_part(int* part, int nc) {
    if (threadIdx.x == 0) {
        int run = 0;
        for (int c = 0; c < nc; c++) { int v = part[c]; part[c] = run; run += v; }
    }
}

__global__ __launch_bounds__(256) void k_scan_add(int* rowptr2, int* cursor2,
                                                  const int* __restrict__ part) {
    int i = blockIdx.x * 256 + threadIdx.x;
    if (i >= NB) return;
    int v = rowptr2[i] + part[i >> 11];
    rowptr2[i] = v;
    cursor2[i] = v;
}

__global__ __launch_bounds__(256) void k_fill(const int* __restrict__ ei,
                                              int* cursor2, int* srcs, int* dsts) {
    int e = blockIdx.x * 256 + threadIdx.x;
    if (e >= EN) return;
    int src, dst;
    if (e < NEDGES) { src = ei[e]; dst = ei[NEDGES + e]; }
    else            { src = dst = e - NEDGES; }
    int pos = atomicAdd(&cursor2[dst * NBW + (src >> WSHIFT)], 1);
    srcs[pos] = src;
    dsts[pos] = dst;
}

// ---------------------------------------------------------------- per-edge coefficients (bucket order)
// evs[e] = exp(leakyrelu(as_[src]+ad_[dst])); ssum[dst] += ev.
// Softmax without max subtraction (shift-invariant; logits O(1) here).
__global__ __launch_bounds__(256) void k_coef(const int* __restrict__ srcs,
                                              const int* __restrict__ dsts,
                                              const float* __restrict__ as_,
                                              const float* __restrict__ ad_,
                                              float* __restrict__ evs,
                                              float* __restrict__ ssum) {
    int e = blockIdx.x * 256 + threadIdx.x;
    if (e >= EN) return;
    int s = srcs[e], d = dsts[e];
    float al = as_[s] + ad_[d];
    al = (al > 0.f) ? al : 0.2f * al;
    float ev = __expf(al);
    evs[e] = ev;
    atomicAdd(&ssum[d], ev);
}

// ---------------------------------------------------------------- GEMM (C[M,128] = A[M,K] @ B[K,128]) -> bf16 C (paired words)
template <int K, bool ABF>
__global__ __launch_bounds__(256) void k_gemm(const void* __restrict__ Av,
                                              const float* __restrict__ B,
                                              u16* __restrict__ C, int M) {
    __shared__ float As[16][128];
    __shared__ float Bs[16][128];
    int bm = blockIdx.x * 128;
    int tid = threadIdx.x;
    int tx = tid & 15, ty = tid >> 4;
    float acc[8][8] = {};
    for (int k0 = 0; k0 < K; k0 += 16) {
#pragma unroll
        for (int q = tid; q < 512; q += 256) {       // A tile -> As[k][m] (transposed)
            int m = q >> 2, kq = (q & 3) << 2;
            int row = bm + m;
            if (ABF) {
                const u16* A = (const u16*)Av;
                uint2 v = make_uint2(0u, 0u);
                if (row < M) v = *(const uint2*)(A + (size_t)row * K + k0 + kq);
                As[kq + 0][m] = bfl(v.x); As[kq + 1][m] = bfh(v.x);
                As[kq + 2][m] = bfl(v.y); As[kq + 3][m] = bfh(v.y);
            } else {
                const float* A = (const float*)Av;
                float4 v = make_float4(0.f, 0.f, 0.f, 0.f);
                if (row < M) v = *(const float4*)(A + (size_t)row * K + k0 + kq);
                As[kq + 0][m] = v.x; As[kq + 1][m] = v.y;
                As[kq + 2][m] = v.z; As[kq + 3][m] = v.w;
            }
        }
#pragma unroll
        for (int q = tid; q < 512; q += 256) {       // B tile
            int kk = q >> 5, n4 = (q & 31) << 2;
            *(float4*)(&Bs[kk][n4]) = *(const float4*)(B + (size_t)(k0 + kk) * 128 + n4);
        }
        __syncthreads();
#pragma unroll
        for (int kk = 0; kk < 16; kk++) {
            float a[8], b[8];
            *(float4*)(a)     = *(float4*)(&As[kk][ty * 8]);
            *(float4*)(a + 4) = *(float4*)(&As[kk][ty * 8 + 4]);
            *(float4*)(b)     = *(float4*)(&Bs[kk][tx * 8]);
            *(float4*)(b + 4) = *(float4*)(&Bs[kk][tx * 8 + 4]);
#pragma unroll
            for (int i = 0; i < 8; i++)
#pragma unroll
                for (int j = 0; j < 8; j++)
                    acc[i][j] = fmaf(a[i], b[j], acc[i][j]);
        }
        __syncthreads();
    }
#pragma unroll
    for (int i = 0; i < 8; i++) {
        int row = bm + ty * 8 + i;
        if (row < M) {
            uint4 o;
            o.x = f2bf(acc[i][0]) | (f2bf(acc[i][1]) << 16);
            o.y = f2bf(acc[i][2]) | (f2bf(acc[i][3]) << 16);
            o.z = f2bf(acc[i][4]) | (f2bf(acc[i][5]) << 16);
            o.w = f2bf(acc[i][6]) | (f2bf(acc[i][7]) << 16);
            *(uint4*)(C + (size_t)row * 128 + tx * 8) = o;
        }
    }
}

// ---------------------------------------------------------------- attention dot products (wave per node, bf16 h)
__global__ __launch_bounds__(256) void k_dots(const u32* __restrict__ h,
                                              const float* __restrict__ asrc,
                                              const float* __restrict__ adst,
                                              float* as_, float* ad_) {
    int wid = (blockIdx.x * 256 + threadIdx.x) >> 6;
    int lane = threadIdx.x & 63;
    if (wid >= NNODES) return;
    u32 u = h[(size_t)wid * 64 + lane];
    float vx = bfl(u), vy = bfh(u);
    float2 as2 = ((const float2*)asrc)[lane];
    float2 ad2 = ((const float2*)adst)[lane];
    float s = vx * as2.x + vy * as2.y;
    float d = vx * ad2.x + vy * ad2.y;
#pragma unroll
    for (int off = 32; off; off >>= 1) {
        s += __shfl_xor(s, off);
        d += __shfl_xor(d, off);
    }
    if (lane == 0) { as_[wid] = s; ad_[wid] = d; }
}

// ---------------------------------------------------------------- windowed partial aggregation (wave per dst, one src-window)
// Launched once per window w (sequential): dispatch order synchronizes the
// whole die onto one 4.2MB h-window -> L2-resident gathers (R10: ~25us per
// 243K-edge launch vs 600us monolithic). Partial float2 accumulators flushed
// to global fp32 acc between launches (L3-resident).
template <bool FIRST>
__global__ __launch_bounds__(256) void k_aggp(
    const u32* __restrict__ h, const int* __restrict__ srcs,
    const float* __restrict__ evs, const int* __restrict__ rowptr2,
    const int* __restrict__ rowend2, float* __restrict__ acc, int w) {
    int wid = (blockIdx.x * 256 + threadIdx.x) >> 6;
    int lane = threadIdx.x & 63;
    if (wid >= NNODES) return;
    int b = wid * NBW + w;
    int e = rowptr2[b], end = rowend2[b];
    float2 a;
    if (FIRST) a = make_float2(0.f, 0.f);
    else       a = ((const float2*)acc)[(size_t)wid * 64 + lane];
    for (; e + 2 <= end; e += 2) {
        int   s0 = srcs[e],  s1 = srcs[e + 1];
        float e0 = evs[e],   e1 = evs[e + 1];
        u32 u0 = h[(size_t)s0 * 64 + lane];
        u32 u1 = h[(size_t)s1 * 64 + lane];
        a.x = fmaf(e0, bfl(u0), a.x); a.y = fmaf(e0, bfh(u0), a.y);
        a.x = fmaf(e1, bfl(u1), a.x); a.y = fmaf(e1, bfh(u1), a.y);
    }
    if (e < end) {
        int s0 = srcs[e]; float e0 = evs[e];
        u32 u0 = h[(size_t)s0 * 64 + lane];
        a.x = fmaf(e0, bfl(u0), a.x); a.y = fmaf(e0, bfh(u0), a.y);
    }
    ((float2*)acc)[(size_t)wid * 64 + lane] = a;
}

// ---------------------------------------------------------------- pure epilogue: normalize + bias (+relu) (+gate) (wave per node)
// NO gathers, NO CSR reads -- isolates the R10 k_aggf 620us mystery.
template <bool RELU, bool OUTBF, bool GATE>
__global__ __launch_bounds__(256) void k_norm(
    const float* __restrict__ acc, const float* __restrict__ ssum,
    const float* __restrict__ bias, void* __restrict__ outv,
    const float* __restrict__ gateW, const float* __restrict__ gateB,
    float* __restrict__ gatev, float* __restrict__ gs,
    const int* __restrict__ batch) {
    int wid = (blockIdx.x * 256 + threadIdx.x) >> 6;
    int lane = threadIdx.x & 63;
    if (wid >= NNODES) return;
    float2 a = ((const float2*)acc)[(size_t)wid * 64 + lane];
    float inv = 1.f / (ssum[wid] + 1e-16f);
    float2 b2v = ((const float2*)bias)[lane];
    float o0 = a.x * inv + b2v.x;
    float o1 = a.y * inv + b2v.y;
    if (RELU) { o0 = fmaxf(o0, 0.f); o1 = fmaxf(o1, 0.f); }
    if (OUTBF) {
        ((u32*)outv)[(size_t)wid * 64 + lane] = f2bf(o0) | (f2bf(o1) << 16);
    } else {
        ((float2*)((float*)outv + (size_t)wid * 128))[lane] = make_float2(o0, o1);
    }
    if (GATE) {
        float2 gw = ((const float2*)gateW)[lane];
        float g = o0 * gw.x + o1 * gw.y;
#pragma unroll
        for (int off = 32; off; off >>= 1) g += __shfl_xor(g, off);
        if (lane == 0) {
            float ge = __expf(g + gateB[0]);   // no max subtraction (shift-invariant)
            gatev[wid] = ge;
            atomicAdd(&gs[batch[wid]], ge);
        }
    }
}

// ---------------------------------------------------------------- attention pooling (batch is sorted)
__global__ __launch_bounds__(128) void k_pool(const float* __restrict__ h,
                                              const float* __restrict__ gatev,
                                              const float* __restrict__ gs,
                                              const int* __restrict__ batch,
                                              float* pooled) {
    int t = threadIdx.x;  // feature
    int chunk = (NNODES + gridDim.x - 1) / gridDim.x;
    int s0 = blockIdx.x * chunk;
    int s1 = s0 + chunk; if (s1 > NNODES) s1 = NNODES;
    if (s0 >= s1) return;
    int curg = batch[s0];
    float invs = 1.f / (gs[curg] + 1e-16f);
    float acc = 0.f;
    for (int i = s0; i < s1; i++) {
        int g = batch[i];
        if (g != curg) {
            atomicAdd(&pooled[curg * 128 + t], acc);
            acc = 0.f; curg = g;
            invs = 1.f / (gs[g] + 1e-16f);
        }
        acc += h[(size_t)i * 128 + t] * (gatev[i] * invs);
    }
    atomicAdd(&pooled[curg * 128 + t], acc);
}

// ---------------------------------------------------------------- final: relu(pooled) @ lin_W + lin_b
__global__ __launch_bounds__(64) void k_final(const float* __restrict__ pooled,
                                              const float* __restrict__ linW,
                                              const float* __restrict__ linb,
                                              float* __restrict__ out) {
    __shared__ float rowv[128];
    int g = blockIdx.x, t = threadIdx.x;
    rowv[t]      = fmaxf(pooled[g * 128 + t], 0.f);
    rowv[t + 64] = fmaxf(pooled[g * 128 + 64 + t], 0.f);
    __syncthreads();
    float acc = linb[t];
#pragma unroll 8
    for (int k = 0; k < 128; k++) acc = fmaf(rowv[k], linW[k * 64 + t], acc);
    out[g * 64 + t] = acc;
}

// ---------------------------------------------------------------- launch
extern "C" void kernel_launch(void* const* d_in, const int* in_sizes, int n_in,
                              void* d_out, int out_size, void* d_ws, size_t ws_size,
                              hipStream_t stream) {
    const float* x     = (const float*)d_in[0];
    const int*   ei    = (const int*)d_in[1];
    const int*   batch = (const int*)d_in[2];
    const float* W1    = (const float*)d_in[3];
    const float* a1s   = (const float*)d_in[4];
    const float* a1d   = (const float*)d_in[5];
    const float* b1    = (const float*)d_in[6];
    const float* W2    = (const float*)d_in[7];
    const float* a2s   = (const float*)d_in[8];
    const float* a2d   = (const float*)d_in[9];
    const float* b2    = (const float*)d_in[10];
    const float* gateW = (const float*)d_in[11];
    const float* gateB = (const float*)d_in[12];
    const float* linW  = (const float*)d_in[13];
    const float* linb  = (const float*)d_in[14];
    float* out = (float*)d_out;

    char* p = (char*)d_ws;
    auto alloc = [&](size_t bytes) -> void* {
        void* r = (void*)p;
        p += (bytes + 255) & ~(size_t)255;
        return r;
    };
    u16*   hb      = (u16*)alloc((size_t)NNODES * 128 * 2);   // GEMM out (bf16 paired words)
    u16*   h1a     = (u16*)alloc((size_t)NNODES * 128 * 2);   // conv1 agg out (bf16)
    float* acc     = (float*)alloc((size_t)NNODES * 128 * 4); // partial accumulator / conv2 fp32 out (in place)
    int*   srcs    = (int*)alloc((size_t)EN * 4);
    int*   dsts    = (int*)alloc((size_t)EN * 4);
    float* evs     = (float*)alloc((size_t)EN * 4);
    int*   cnt2    = (int*)alloc((size_t)NB * 4);
    int*   rowptr2 = (int*)alloc((size_t)NB * 4);
    int*   cursor2 = (int*)alloc((size_t)NB * 4);
    float* as_     = (float*)alloc((size_t)NNODES * 4);
    float* ad_     = (float*)alloc((size_t)NNODES * 4);
    float* gatev   = (float*)alloc((size_t)NNODES * 4);
    float* ssum    = (float*)alloc((size_t)NNODES * 4);
    int*   part    = (int*)alloc(512 * 4);
    float* gs      = (float*)alloc(NG * 4);
    float* pooled  = (float*)alloc((size_t)NG * HID * 4);

    const int gN  = (NNODES + 255) / 256;      // 391
    const int gEN = (EN + 255) / 256;
    const int gB  = (NB + 255) / 256;          // 2735
    const int gW  = (NNODES + 3) / 4;          // wave-per-node, 4 waves/block

    // bucketed dst-CSR build (key = dst*7 + src-window), shared by both convs
    k_init<<<gN, 256, 0, stream>>>(gs, pooled, ssum);
    k_cnt_init<<<gB, 256, 0, stream>>>(cnt2);
    k_count2<<<gEN, 256, 0, stream>>>(ei, cnt2);
    k_scan_chunk<<<NCHUNK2, 256, 0, stream>>>(cnt2, rowptr2, part);
    k_scan_part<<<1, 64, 0, stream>>>(part, NCHUNK2);
    k_scan_add<<<gB, 256, 0, stream>>>(rowptr2, cursor2, part);
    k_fill<<<gEN, 256, 0, stream>>>(ei, cursor2, srcs, dsts);
    // after k_fill, cursor2[b] == bucket end

    // conv1
    k_gemm<256, false><<<(NNODES + 127) / 128, 256, 0, stream>>>(x, W1, hb, NNODES);
    k_dots<<<gW, 256, 0, stream>>>((const u32*)hb, a1s, a1d, as_, ad_);
    k_coef<<<gEN, 256, 0, stream>>>(srcs, dsts, as_, ad_, evs, ssum);
    k_aggp<true><<<gW, 256, 0, stream>>>((const u32*)hb, srcs, evs, rowptr2, cursor2, acc, 0);
    for (int w = 1; w < NBW; w++)
        k_aggp<false><<<gW, 256, 0, stream>>>((const u32*)hb, srcs, evs, rowptr2, cursor2, acc, w);
    k_norm<true, true, false><<<gW, 256, 0, stream>>>(acc, ssum, b1, h1a,
                                                      nullptr, nullptr, nullptr,
                                                      nullptr, nullptr);
    // conv2
    k_zs<<<gN, 256, 0, stream>>>(ssum);
    k_gemm<128, true><<<(NNODES + 127) / 128, 256, 0, stream>>>(h1a, W2, hb, NNODES);
    k_dots<<<gW, 256, 0, stream>>>((const u32*)hb, a2s, a2d, as_, ad_);
    k_coef<<<gEN, 256, 0, stream>>>(srcs, dsts, as_, ad_, evs, ssum);
    k_aggp<true><<<gW, 256, 0, stream>>>((const u32*)hb, srcs, evs, rowptr2, cursor2, acc, 0);
    for (int w = 1; w < NBW; w++)
        k_aggp<false><<<gW, 256, 0, stream>>>((const u32*)hb, srcs, evs, rowptr2, cursor2, acc, w);
    k_norm<false, false, true><<<gW, 256, 0, stream>>>(acc, ssum, b2, acc,
                                                       gateW, gateB, gatev, gs, batch);
    // global attention pooling + final linear
    k_pool<<<512, 128, 0, stream>>>(acc, gatev, gs, batch, pooled);
    k_final<<<NG, 64, 0, stream>>>(pooled, linW, linb, out);
}

// Round 12
// 1212.419 us; speedup vs baseline: 1.4810x; 1.4810x over previous
//
#include <hip/hip_runtime.h>
#include <hip/hip_bf16.h>
#include <math.h>

#define NNODES 100000
#define NEDGES 1600000
#define EN     1700000                      // edges + self loops
#define NBW    7                            // src windows (16384 nodes each)
#define WSHIFT 14
#define NB     (NNODES * NBW)               // total (dst,window) buckets = 700000
#define F_IN   256
#define F_MID  128
#define HID    128
#define NG     128
#define NOUT   64
#define SCAN_CHUNK 2048
#define NCHUNK2 ((NB + SCAN_CHUNK - 1) / SCAN_CHUNK)   // 342

typedef unsigned int  u32;
typedef unsigned short u16;

__device__ __forceinline__ float bfl(u32 u) { return __uint_as_float(u << 16); }
__device__ __forceinline__ float bfh(u32 u) { return __uint_as_float(u & 0xFFFF0000u); }
__device__ __forceinline__ u32 f2bf(float f) {           // round-to-nearest-even
    u32 x = __float_as_uint(f);
    return (x + 0x7FFFu + ((x >> 16) & 1u)) >> 16;
}

// ---------------------------------------------------------------- init
__global__ __launch_bounds__(256) void k_init(float* gs, float* pooled, float* ssum) {
    int i = blockIdx.x * 256 + threadIdx.x;
    if (i < NNODES) ssum[i] = 0.f;
    if (i < NG) gs[i] = 0.f;
    if (i < NG * HID) pooled[i] = 0.f;
}

__global__ __launch_bounds__(256) void k_zs(float* ssum) {
    int i = blockIdx.x * 256 + threadIdx.x;
    if (i < NNODES) ssum[i] = 0.f;
}

__global__ __launch_bounds__(256) void k_cnt_init(int* cnt2) {
    int i = blockIdx.x * 256 + threadIdx.x;
    if (i < NB) cnt2[i] = 0;
}

// ---------------------------------------------------------------- bucketed CSR build: key = dst*NBW + (src>>WSHIFT)
__global__ __launch_bounds__(256) void k_count2(const int* __restrict__ ei, int* cnt2) {
    int e = blockIdx.x * 256 + threadIdx.x;
    if (e >= EN) return;
    int src, dst;
    if (e < NEDGES) { src = ei[e]; dst = ei[NEDGES + e]; }
    else            { src = dst = e - NEDGES; }
    atomicAdd(&cnt2[dst * NBW + (src >> WSHIFT)], 1);
}

__global__ __launch_bounds__(256) void k_scan_chunk(const int* __restrict__ cnt2,
                                                    int* rowptr2, int* part) {
    __shared__ int sums[256];
    int c = blockIdx.x, t = threadIdx.x;
    int base = c * SCAN_CHUNK;
    int v[8]; int s = 0;
#pragma unroll
    for (int i = 0; i < 8; i++) {
        int idx = base + t * 8 + i;
        v[i] = (idx < NB) ? cnt2[idx] : 0;
        s += v[i];
    }
    sums[t] = s;
    __syncthreads();
    for (int off = 1; off < 256; off <<= 1) {
        int x = (t >= off) ? sums[t - off] : 0;
        __syncthreads();
        sums[t] += x;
        __syncthreads();
    }
    int run = (t == 0) ? 0 : sums[t - 1];
#pragma unroll
    for (int i = 0; i < 8; i++) {
        int idx = base + t * 8 + i;
        if (idx < NB) rowptr2[idx] = run;
        run += v[i];
    }
    if (t == 255) part[c] = sums[255];
}

__global__ void k_scan_part(int* part, int nc) {
    if (threadIdx.x == 0) {
        int run = 0;
        for (int c = 0; c < nc; c++) { int v = part[c]; part[c] = run; run += v; }
    }
}

__global__ __launch_bounds__(256) void k_scan_add(int* rowptr2, int* cursor2,
                                                  const int* __restrict__ part) {
    int i = blockIdx.x * 256 + threadIdx.x;
    if (i >= NB) return;
    int v = rowptr2[i] + part[i >> 11];
    rowptr2[i] = v;
    cursor2[i] = v;
}

__global__ __launch_bounds__(256) void k_fill(const int* __restrict__ ei,
                                              int* cursor2, int* srcs, int* dsts) {
    int e = blockIdx.x * 256 + threadIdx.x;
    if (e >= EN) return;
    int src, dst;
    if (e < NEDGES) { src = ei[e]; dst = ei[NEDGES + e]; }
    else            { src = dst = e - NEDGES; }
    int pos = atomicAdd(&cursor2[dst * NBW + (src >> WSHIFT)], 1);
    srcs[pos] = src;
    dsts[pos] = dst;
}

// ---------------------------------------------------------------- per-edge coefficients (bucket order)
// evs[e] = exp(leakyrelu(as_[src]+ad_[dst])); ssum[dst] += ev.
// Softmax without max subtraction (shift-invariant; logits O(1) here).
__global__ __launch_bounds__(256) void k_coef(const int* __restrict__ srcs,
                                              const int* __restrict__ dsts,
                                              const float* __restrict__ as_,
                                              const float* __restrict__ ad_,
                                              float* __restrict__ evs,
                                              float* __restrict__ ssum) {
    int e = blockIdx.x * 256 + threadIdx.x;
    if (e >= EN) return;
    int s = srcs[e], d = dsts[e];
    float al = as_[s] + ad_[d];
    al = (al > 0.f) ? al : 0.2f * al;
    float ev = __expf(al);
    evs[e] = ev;
    atomicAdd(&ssum[d], ev);
}

// ---------------------------------------------------------------- GEMM (C[M,128] = A[M,K] @ B[K,128]) -> bf16 C (paired words)
template <int K, bool ABF>
__global__ __launch_bounds__(256) void k_gemm(const void* __restrict__ Av,
                                              const float* __restrict__ B,
                                              u16* __restrict__ C, int M) {
    __shared__ float As[16][128];
    __shared__ float Bs[16][128];
    int bm = blockIdx.x * 128;
    int tid = threadIdx.x;
    int tx = tid & 15, ty = tid >> 4;
    float acc[8][8] = {};
    for (int k0 = 0; k0 < K; k0 += 16) {
#pragma unroll
        for (int q = tid; q < 512; q += 256) {       // A tile -> As[k][m] (transposed)
            int m = q >> 2, kq = (q & 3) << 2;
            int row = bm + m;
            if (ABF) {
                const u16* A = (const u16*)Av;
                uint2 v = make_uint2(0u, 0u);
                if (row < M) v = *(const uint2*)(A + (size_t)row * K + k0 + kq);
                As[kq + 0][m] = bfl(v.x); As[kq + 1][m] = bfh(v.x);
                As[kq + 2][m] = bfl(v.y); As[kq + 3][m] = bfh(v.y);
            } else {
                const float* A = (const float*)Av;
                float4 v = make_float4(0.f, 0.f, 0.f, 0.f);
                if (row < M) v = *(const float4*)(A + (size_t)row * K + k0 + kq);
                As[kq + 0][m] = v.x; As[kq + 1][m] = v.y;
                As[kq + 2][m] = v.z; As[kq + 3][m] = v.w;
            }
        }
#pragma unroll
        for (int q = tid; q < 512; q += 256) {       // B tile
            int kk = q >> 5, n4 = (q & 31) << 2;
            *(float4*)(&Bs[kk][n4]) = *(const float4*)(B + (size_t)(k0 + kk) * 128 + n4);
        }
        __syncthreads();
#pragma unroll
        for (int kk = 0; kk < 16; kk++) {
            float a[8], b[8];
            *(float4*)(a)     = *(float4*)(&As[kk][ty * 8]);
            *(float4*)(a + 4) = *(float4*)(&As[kk][ty * 8 + 4]);
            *(float4*)(b)     = *(float4*)(&Bs[kk][tx * 8]);
            *(float4*)(b + 4) = *(float4*)(&Bs[kk][tx * 8 + 4]);
#pragma unroll
            for (int i = 0; i < 8; i++)
#pragma unroll
                for (int j = 0; j < 8; j++)
                    acc[i][j] = fmaf(a[i], b[j], acc[i][j]);
        }
        __syncthreads();
    }
#pragma unroll
    for (int i = 0; i < 8; i++) {
        int row = bm + ty * 8 + i;
        if (row < M) {
            uint4 o;
            o.x = f2bf(acc[i][0]) | (f2bf(acc[i][1]) << 16);
            o.y = f2bf(acc[i][2]) | (f2bf(acc[i][3]) << 16);
            o.z = f2bf(acc[i][4]) | (f2bf(acc[i][5]) << 16);
            o.w = f2bf(acc[i][6]) | (f2bf(acc[i][7]) << 16);
            *(uint4*)(C + (size_t)row * 128 + tx * 8) = o;
        }
    }
}

// ---------------------------------------------------------------- attention dot products (wave per node, bf16 h)
__global__ __launch_bounds__(256) void k_dots(const u32* __restrict__ h,
                                              const float* __restrict__ asrc,
                                              const float* __restrict__ adst,
                                              float* as_, float* ad_) {
    int wid = (blockIdx.x * 256 + threadIdx.x) >> 6;
    int lane = threadIdx.x & 63;
    if (wid >= NNODES) return;
    u32 u = h[(size_t)wid * 64 + lane];
    float vx = bfl(u), vy = bfh(u);
    float2 as2 = ((const float2*)asrc)[lane];
    float2 ad2 = ((const float2*)adst)[lane];
    float s = vx * as2.x + vy * as2.y;
    float d = vx * ad2.x + vy * ad2.y;
#pragma unroll
    for (int off = 32; off; off >>= 1) {
        s += __shfl_xor(s, off);
        d += __shfl_xor(d, off);
    }
    if (lane == 0) { as_[wid] = s; ad_[wid] = d; }
}

// ---------------------------------------------------------------- windowed partial aggregation (wave per dst, one src-window)
// Launched once per window w (sequential): dispatch order synchronizes the
// whole die onto one 4.2MB h-window -> L2-resident gathers (R10: ~25us per
// 243K-edge launch vs 600us monolithic). Partial float2 accumulators flushed
// to global fp32 acc between launches (L3-resident).
template <bool FIRST>
__global__ __launch_bounds__(256) void k_aggp(
    const u32* __restrict__ h, const int* __restrict__ srcs,
    const float* __restrict__ evs, const int* __restrict__ rowptr2,
    const int* __restrict__ rowend2, float* __restrict__ acc, int w) {
    int wid = (blockIdx.x * 256 + threadIdx.x) >> 6;
    int lane = threadIdx.x & 63;
    if (wid >= NNODES) return;
    int b = wid * NBW + w;
    int e = rowptr2[b], end = rowend2[b];
    float2 a;
    if (FIRST) a = make_float2(0.f, 0.f);
    else       a = ((const float2*)acc)[(size_t)wid * 64 + lane];
    for (; e + 2 <= end; e += 2) {
        int   s0 = srcs[e],  s1 = srcs[e + 1];
        float e0 = evs[e],   e1 = evs[e + 1];
        u32 u0 = h[(size_t)s0 * 64 + lane];
        u32 u1 = h[(size_t)s1 * 64 + lane];
        a.x = fmaf(e0, bfl(u0), a.x); a.y = fmaf(e0, bfh(u0), a.y);
        a.x = fmaf(e1, bfl(u1), a.x); a.y = fmaf(e1, bfh(u1), a.y);
    }
    if (e < end) {
        int s0 = srcs[e]; float e0 = evs[e];
        u32 u0 = h[(size_t)s0 * 64 + lane];
        a.x = fmaf(e0, bfl(u0), a.x); a.y = fmaf(e0, bfh(u0), a.y);
    }
    ((float2*)acc)[(size_t)wid * 64 + lane] = a;
}

// ---------------------------------------------------------------- flat epilogue: normalize + bias (+relu), NO gate, NO atomics
// k_zero-shaped flat stream (proven fast). Thread i handles features
// (2w, 2w+1) of node i>>6, w = i&63. 25000 blocks x 256 threads exactly.
template <bool RELU, bool OUTBF>
__global__ __launch_bounds__(256) void k_norm(
    const float* __restrict__ acc, const float* __restrict__ ssum,
    const float* __restrict__ bias, void* __restrict__ outv) {
    int i = blockIdx.x * 256 + threadIdx.x;      // i < NNODES*64
    int node = i >> 6, w = i & 63;
    float2 a = ((const float2*)acc)[i];
    float inv = 1.f / (ssum[node] + 1e-16f);
    float2 bv = ((const float2*)bias)[w];
    float o0 = a.x * inv + bv.x;
    float o1 = a.y * inv + bv.y;
    if (RELU) { o0 = fmaxf(o0, 0.f); o1 = fmaxf(o1, 0.f); }
    if (OUTBF) ((u32*)outv)[i] = f2bf(o0) | (f2bf(o1) << 16);
    else       ((float2*)outv)[i] = make_float2(o0, o1);
}

// ---------------------------------------------------------------- gate logits (k_dots-shaped, wave per node, NO atomics)
__global__ __launch_bounds__(256) void k_gate(const float* __restrict__ h2,
                                              const float* __restrict__ gateW,
                                              const float* __restrict__ gateB,
                                              float* __restrict__ gatev) {
    int wid = (blockIdx.x * 256 + threadIdx.x) >> 6;
    int lane = threadIdx.x & 63;
    if (wid >= NNODES) return;
    float2 v  = ((const float2*)(h2 + (size_t)wid * 128))[lane];
    float2 gw = ((const float2*)gateW)[lane];
    float g = v.x * gw.x + v.y * gw.y;
#pragma unroll
    for (int off = 32; off; off >>= 1) g += __shfl_xor(g, off);
    if (lane == 0) gatev[wid] = __expf(g + gateB[0]);   // no max subtraction (shift-invariant)
}

// ---------------------------------------------------------------- gate segment-sum: one block per graph, binary search, ZERO atomics
__global__ __launch_bounds__(256) void k_gsum(const float* __restrict__ gatev,
                                              const int* __restrict__ batch,
                                              float* __restrict__ gs) {
    int g = blockIdx.x;
    // lower_bound(batch, g) and lower_bound(batch, g+1) -- batch is sorted
    int lo = 0, hi = NNODES;
    while (lo < hi) { int mid = (lo + hi) >> 1; if (batch[mid] < g) lo = mid + 1; else hi = mid; }
    int s0 = lo;
    hi = NNODES;
    while (lo < hi) { int mid = (lo + hi) >> 1; if (batch[mid] < g + 1) lo = mid + 1; else hi = mid; }
    int s1 = lo;
    float a = 0.f;
    for (int i = s0 + threadIdx.x; i < s1; i += 256) a += gatev[i];
#pragma unroll
    for (int off = 32; off; off >>= 1) a += __shfl_xor(a, off);
    __shared__ float red[4];
    int wv = threadIdx.x >> 6;
    if ((threadIdx.x & 63) == 0) red[wv] = a;
    __syncthreads();
    if (threadIdx.x == 0) gs[g] = (red[0] + red[1]) + (red[2] + red[3]);
}

// ---------------------------------------------------------------- attention pooling (batch is sorted)
__global__ __launch_bounds__(128) void k_pool(const float* __restrict__ h,
                                              const float* __restrict__ gatev,
                                              const float* __restrict__ gs,
                                              const int* __restrict__ batch,
                                              float* pooled) {
    int t = threadIdx.x;  // feature
    int chunk = (NNODES + gridDim.x - 1) / gridDim.x;
    int s0 = blockIdx.x * chunk;
    int s1 = s0 + chunk; if (s1 > NNODES) s1 = NNODES;
    if (s0 >= s1) return;
    int curg = batch[s0];
    float invs = 1.f / (gs[curg] + 1e-16f);
    float acc = 0.f;
    for (int i = s0; i < s1; i++) {
        int g = batch[i];
        if (g != curg) {
            atomicAdd(&pooled[curg * 128 + t], acc);
            acc = 0.f; curg = g;
            invs = 1.f / (gs[g] + 1e-16f);
        }
        acc += h[(size_t)i * 128 + t] * (gatev[i] * invs);
    }
    atomicAdd(&pooled[curg * 128 + t], acc);
}

// ---------------------------------------------------------------- final: relu(pooled) @ lin_W + lin_b
__global__ __launch_bounds__(64) void k_final(const float* __restrict__ pooled,
                                              const float* __restrict__ linW,
                                              const float* __restrict__ linb,
                                              float* __restrict__ out) {
    __shared__ float rowv[128];
    int g = blockIdx.x, t = threadIdx.x;
    rowv[t]      = fmaxf(pooled[g * 128 + t], 0.f);
    rowv[t + 64] = fmaxf(pooled[g * 128 + 64 + t], 0.f);
    __syncthreads();
    float acc = linb[t];
#pragma unroll 8
    for (int k = 0; k < 128; k++) acc = fmaf(rowv[k], linW[k * 64 + t], acc);
    out[g * 64 + t] = acc;
}

// ---------------------------------------------------------------- launch
extern "C" void kernel_launch(void* const* d_in, const int* in_sizes, int n_in,
                              void* d_out, int out_size, void* d_ws, size_t ws_size,
                              hipStream_t stream) {
    const float* x     = (const float*)d_in[0];
    const int*   ei    = (const int*)d_in[1];
    const int*   batch = (const int*)d_in[2];
    const float* W1    = (const float*)d_in[3];
    const float* a1s   = (const float*)d_in[4];
    const float* a1d   = (const float*)d_in[5];
    const float* b1    = (const float*)d_in[6];
    const float* W2    = (const float*)d_in[7];
    const float* a2s   = (const float*)d_in[8];
    const float* a2d   = (const float*)d_in[9];
    const float* b2    = (const float*)d_in[10];
    const float* gateW = (const float*)d_in[11];
    const float* gateB = (const float*)d_in[12];
    const float* linW  = (const float*)d_in[13];
    const float* linb  = (const float*)d_in[14];
    float* out = (float*)d_out;

    char* p = (char*)d_ws;
    auto alloc = [&](size_t bytes) -> void* {
        void* r = (void*)p;
        p += (bytes + 255) & ~(size_t)255;
        return r;
    };
    u16*   hb      = (u16*)alloc((size_t)NNODES * 128 * 2);   // GEMM out (bf16 paired words)
    u16*   h1a     = (u16*)alloc((size_t)NNODES * 128 * 2);   // conv1 agg out (bf16)
    // h2 (conv2 fp32 out, 51.2MB) aliases hb+h1a (contiguous, both dead by then)
    float* h2      = (float*)hb;
    float* acc     = (float*)alloc((size_t)NNODES * 128 * 4); // partial accumulator
    int*   srcs    = (int*)alloc((size_t)EN * 4);
    int*   dsts    = (int*)alloc((size_t)EN * 4);
    float* evs     = (float*)alloc((size_t)EN * 4);
    int*   cnt2    = (int*)alloc((size_t)NB * 4);
    int*   rowptr2 = (int*)alloc((size_t)NB * 4);
    int*   cursor2 = (int*)alloc((size_t)NB * 4);
    float* as_     = (float*)alloc((size_t)NNODES * 4);
    float* ad_     = (float*)alloc((size_t)NNODES * 4);
    float* gatev   = (float*)alloc((size_t)NNODES * 4);
    float* ssum    = (float*)alloc((size_t)NNODES * 4);
    int*   part    = (int*)alloc(512 * 4);
    float* gs      = (float*)alloc(NG * 4);
    float* pooled  = (float*)alloc((size_t)NG * HID * 4);

    const int gN  = (NNODES + 255) / 256;      // 391
    const int gEN = (EN + 255) / 256;
    const int gB  = (NB + 255) / 256;          // 2735
    const int gW  = (NNODES + 3) / 4;          // wave-per-node, 4 waves/block
    const int gF  = NNODES * 64 / 256;         // flat norm grid, 25000 exact

    // bucketed dst-CSR build (key = dst*7 + src-window), shared by both convs
    k_init<<<gN, 256, 0, stream>>>(gs, pooled, ssum);
    k_cnt_init<<<gB, 256, 0, stream>>>(cnt2);
    k_count2<<<gEN, 256, 0, stream>>>(ei, cnt2);
    k_scan_chunk<<<NCHUNK2, 256, 0, stream>>>(cnt2, rowptr2, part);
    k_scan_part<<<1, 64, 0, stream>>>(part, NCHUNK2);
    k_scan_add<<<gB, 256, 0, stream>>>(rowptr2, cursor2, part);
    k_fill<<<gEN, 256, 0, stream>>>(ei, cursor2, srcs, dsts);
    // after k_fill, cursor2[b] == bucket end

    // conv1
    k_gemm<256, false><<<(NNODES + 127) / 128, 256, 0, stream>>>(x, W1, hb, NNODES);
    k_dots<<<gW, 256, 0, stream>>>((const u32*)hb, a1s, a1d, as_, ad_);
    k_coef<<<gEN, 256, 0, stream>>>(srcs, dsts, as_, ad_, evs, ssum);
    k_aggp<true><<<gW, 256, 0, stream>>>((const u32*)hb, srcs, evs, rowptr2, cursor2, acc, 0);
    for (int w = 1; w < NBW; w++)
        k_aggp<false><<<gW, 256, 0, stream>>>((const u32*)hb, srcs, evs, rowptr2, cursor2, acc, w);
    k_norm<true, true><<<gF, 256, 0, stream>>>(acc, ssum, b1, h1a);
    // conv2
    k_zs<<<gN, 256, 0, stream>>>(ssum);
    k_gemm<128, true><<<(NNODES + 127) / 128, 256, 0, stream>>>(h1a, W2, hb, NNODES);
    k_dots<<<gW, 256, 0, stream>>>((const u32*)hb, a2s, a2d, as_, ad_);
    k_coef<<<gEN, 256, 0, stream>>>(srcs, dsts, as_, ad_, evs, ssum);
    k_aggp<true><<<gW, 256, 0, stream>>>((const u32*)hb, srcs, evs, rowptr2, cursor2, acc, 0);
    for (int w = 1; w < NBW; w++)
        k_aggp<false><<<gW, 256, 0, stream>>>((const u32*)hb, srcs, evs, rowptr2, cursor2, acc, w);
    k_norm<false, false><<<gF, 256, 0, stream>>>(acc, ssum, b2, h2);   // h2 overwrites hb region (dead)
    // gate: logits (no atomics) -> per-graph block-reduce (no atomics)
    k_gate<<<gW, 256, 0, stream>>>(h2, gateW, gateB, gatev);
    k_gsum<<<NG, 256, 0, stream>>>(gatev, batch, gs);
    // global attention pooling + final linear
    k_pool<<<512, 128, 0, stream>>>(h2, gatev, gs, batch, pooled);
    k_final<<<NG, 64, 0, stream>>>(pooled, linW, linb, out);
}